// Round 11
// baseline (213.069 us; speedup 1.0000x reference)
//
#include <hip/hip_runtime.h>
#include <math.h>
#include <type_traits>
#include <utility>

#if defined(__has_builtin)
#if __has_builtin(__builtin_amdgcn_rcpf)
#define FAST_RCPF(x) __builtin_amdgcn_rcpf(x)
#endif
#if __has_builtin(__builtin_amdgcn_rsqf)
#define FAST_RSQF(x) __builtin_amdgcn_rsqf(x)
#endif
#endif
#ifndef FAST_RCPF
#define FAST_RCPF(x) (1.0f / (x))
#endif
#ifndef FAST_RSQF
#define FAST_RSQF(x) (1.0f / sqrtf(x))
#endif

// packed lower-tri index (constexpr -> folds in templates)
__host__ __device__ constexpr int PIX(int i, int j) { return i * (i + 1) / 2 + j; }

// ============================================================
// static_for: source-level unrolling. RULE (R6/R7): SROA runs BEFORE loop
// unrolling and never re-runs -> template recursion emits literal-constant
// indices so the first SROA pass promotes allocas to registers.
// RULE (R9): never merge the 45-double solver into a streaming kernel --
// the shared VGPR budget re-spills it. Solver lives in its own kernel.
// ============================================================
template <int N, int I = 0, typename F>
__device__ __forceinline__ void static_for(F&& f) {
  if constexpr (I < N) {
    f(std::integral_constant<int, I>{});
    static_for<N, I + 1>(static_cast<F&&>(f));
  }
}

// ---------- 9x9 packed Cholesky, template-indexed ----------
template <int I, int J, int K>
__device__ __forceinline__ double csub9(const double* M, double s) {
  if constexpr (K >= J) return s;
  else return csub9<I, J, K + 1>(M, s - M[PIX(I, K)] * M[PIX(J, K)]);
}
template <int I, int J>
__device__ __forceinline__ void cholJ(double* M) {
  if constexpr (J <= I) {
    double s = csub9<I, J, 0>(M, M[PIX(I, J)]);
    if constexpr (J == I)
      M[PIX(I, I)] = sqrt(fmax(s, 1e-300));
    else
      M[PIX(I, J)] = s / M[PIX(J, J)];
    cholJ<I, J + 1>(M);
  }
}
template <int I>
__device__ __forceinline__ void cholI(double* M) {
  if constexpr (I < 9) {
    cholJ<I, 0>(M);
    cholI<I + 1>(M);
  }
}

// ---------- forward/backward substitution, template-indexed ----------
template <int I, int K>
__device__ __forceinline__ double fsub9(const double* L, const double* x, double s) {
  if constexpr (K >= I) return s;
  else return fsub9<I, K + 1>(L, x, s - L[PIX(I, K)] * x[K]);
}
template <int I>
__device__ __forceinline__ void fwd9(const double* L, double* x) {
  if constexpr (I < 9) {
    x[I] = fsub9<I, 0>(L, x, x[I]) / L[PIX(I, I)];
    fwd9<I + 1>(L, x);
  }
}
template <int I, int K>
__device__ __forceinline__ double bsub9(const double* L, const double* x, double s) {
  if constexpr (K >= 9) return s;
  else return bsub9<I, K + 1>(L, x, s - L[PIX(K, I)] * x[K]);
}
template <int I>
__device__ __forceinline__ void bwd9(const double* L, double* x) {
  if constexpr (I >= 0) {
    x[I] = bsub9<I, I + 1>(L, x, x[I]) / L[PIX(I, I)];
    bwd9<I - 1>(L, x);
  }
}

// ---------- AtA rank-1 update (45 packed entries), template-indexed ----------
template <int I, int J>
__device__ __forceinline__ void ataIJ(double* M, const double (&a)[9], double w) {
  if constexpr (J <= I) {
    M[PIX(I, J)] += w * a[I] * a[J];
    ataIJ<I, J + 1>(M, a, w);
  }
}
template <int I>
__device__ __forceinline__ void ataI(double* M, const double (&a)[9], double w) {
  if constexpr (I < 9) {
    ataIJ<I, 0>(M, a, w);
    ataI<I + 1>(M, a, w);
  }
}

// ---------- 3x3 Jacobi rotation on named scalars (no arrays at all) ----------
#define JROT(P, Q)                                                              \
  {                                                                             \
    double apq = a##P##Q;                                                       \
    if (fabs(apq) >= 1e-300) {                                                  \
      double tau = (a##Q##Q - a##P##P) / (2.0 * apq);                           \
      double t = ((tau >= 0.0) ? 1.0 : -1.0) / (fabs(tau) + sqrt(1.0 + tau * tau)); \
      double c = 1.0 / sqrt(1.0 + t * t);                                       \
      double s = t * c;                                                         \
      double t0p = a0##P, t0q = a0##Q;                                          \
      a0##P = c * t0p - s * t0q; a0##Q = s * t0p + c * t0q;                     \
      double t1p = a1##P, t1q = a1##Q;                                          \
      a1##P = c * t1p - s * t1q; a1##Q = s * t1p + c * t1q;                     \
      double t2p = a2##P, t2q = a2##Q;                                          \
      a2##P = c * t2p - s * t2q; a2##Q = s * t2p + c * t2q;                     \
      double rp0 = a##P##0, rq0 = a##Q##0;                                      \
      a##P##0 = c * rp0 - s * rq0; a##Q##0 = s * rp0 + c * rq0;                 \
      double rp1 = a##P##1, rq1 = a##Q##1;                                      \
      a##P##1 = c * rp1 - s * rq1; a##Q##1 = s * rp1 + c * rq1;                 \
      double rp2 = a##P##2, rq2 = a##Q##2;                                      \
      a##P##2 = c * rp2 - s * rq2; a##Q##2 = s * rp2 + c * rq2;                 \
      double u0p = V0##P, u0q = V0##Q;                                          \
      V0##P = c * u0p - s * u0q; V0##Q = s * u0p + c * u0q;                     \
      double u1p = V1##P, u1q = V1##Q;                                          \
      V1##P = c * u1p - s * u1q; V1##Q = s * u1p + c * u1q;                     \
      double u2p = V2##P, u2q = V2##Q;                                          \
      V2##P = c * u2p - s * u2q; V2##Q = s * u2p + c * u2q;                     \
    }                                                                           \
  }

// ---------- full solver: null vec of AtA -> rank-2 -> denormalize ----------
__device__ __forceinline__ void solveF(double* M, double s1, double m1x, double m1y,
                                       double s2, double m2x, double m2y,
                                       float* out) {
  double tr = M[0] + M[2] + M[5] + M[9] + M[14] + M[20] + M[27] + M[35] + M[44];
  double shift = 1e-12 * tr;
  M[0] += shift; M[2] += shift; M[5] += shift; M[9] += shift; M[14] += shift;
  M[20] += shift; M[27] += shift; M[35] += shift; M[44] += shift;
  cholI<0>(M);
  double x[9];
  static_for<9>([&](auto i) { x[i] = 1.0; });
  static_for<3>([&](auto) {
    fwd9<0>(M, x);
    bwd9<8>(M, x);
    double n = 0.0;
    static_for<9>([&](auto i) { n += x[i] * x[i]; });
    n = 1.0 / sqrt(n);
    static_for<9>([&](auto i) { x[i] *= n; });
  });
  const double g00 = x[0] * x[0] + x[3] * x[3] + x[6] * x[6];
  const double g01 = x[0] * x[1] + x[3] * x[4] + x[6] * x[7];
  const double g02 = x[0] * x[2] + x[3] * x[5] + x[6] * x[8];
  const double g11 = x[1] * x[1] + x[4] * x[4] + x[7] * x[7];
  const double g12 = x[1] * x[2] + x[4] * x[5] + x[7] * x[8];
  const double g22 = x[2] * x[2] + x[5] * x[5] + x[8] * x[8];
  double a00 = g00, a01 = g01, a02 = g02;
  double a10 = g01, a11 = g11, a12 = g12;
  double a20 = g02, a21 = g12, a22 = g22;
  double V00 = 1, V01 = 0, V02 = 0;
  double V10 = 0, V11 = 1, V12 = 0;
  double V20 = 0, V21 = 0, V22 = 1;
  for (int sweep = 0; sweep < 6; ++sweep) {
    JROT(0, 1);
    JROT(0, 2);
    JROT(1, 2);
  }
  double mv = a00, v0 = V00, v1 = V10, v2 = V20;
  if (a11 < mv) { mv = a11; v0 = V01; v1 = V11; v2 = V21; }
  if (a22 < mv) { mv = a22; v0 = V02; v1 = V12; v2 = V22; }
  const double fv0 = x[0] * v0 + x[1] * v1 + x[2] * v2;
  const double fv1 = x[3] * v0 + x[4] * v1 + x[5] * v2;
  const double fv2 = x[6] * v0 + x[7] * v1 + x[8] * v2;
  const double F200 = x[0] - fv0 * v0, F201 = x[1] - fv0 * v1, F202 = x[2] - fv0 * v2;
  const double F210 = x[3] - fv1 * v0, F211 = x[4] - fv1 * v1, F212 = x[5] - fv1 * v2;
  const double F220 = x[6] - fv2 * v0, F221 = x[7] - fv2 * v1, F222 = x[8] - fv2 * v2;
  const double R00 = s2 * F200, R01 = s2 * F201, R02 = s2 * F202;
  const double R10 = s2 * F210, R11 = s2 * F211, R12 = s2 * F212;
  const double R20 = -s2 * m2x * F200 - s2 * m2y * F210 + F220;
  const double R21 = -s2 * m2x * F201 - s2 * m2y * F211 + F221;
  const double R22 = -s2 * m2x * F202 - s2 * m2y * F212 + F222;
  const double Ff00 = s1 * R00, Ff01 = s1 * R01;
  const double Ff02 = -s1 * m1x * R00 - s1 * m1y * R01 + R02;
  const double Ff10 = s1 * R10, Ff11 = s1 * R11;
  const double Ff12 = -s1 * m1x * R10 - s1 * m1y * R11 + R12;
  const double Ff20 = s1 * R20, Ff21 = s1 * R21;
  const double Ff22 = -s1 * m1x * R20 - s1 * m1y * R21 + R22;
  const double inv = 1.0 / Ff22;
  out[0] = (float)(Ff00 * inv); out[1] = (float)(Ff01 * inv); out[2] = (float)(Ff02 * inv);
  out[3] = (float)(Ff10 * inv); out[4] = (float)(Ff11 * inv); out[5] = (float)(Ff12 * inv);
  out[6] = (float)(Ff20 * inv); out[7] = (float)(Ff21 * inv); out[8] = (float)(Ff22 * inv);
}

// ============================================================
// Sampson terms (z==1.0 exactly; elision is bit-identical)
// ============================================================
struct F9 {
  float f0, f1, f2, f3, f4, f5, f6, f7, f8;
};

__device__ __forceinline__ F9 loadF(const float* __restrict__ p) {
  F9 F;
  F.f0 = p[0]; F.f1 = p[1]; F.f2 = p[2];
  F.f3 = p[3]; F.f4 = p[4]; F.f5 = p[5];
  F.f6 = p[6]; F.f7 = p[7]; F.f8 = p[8];
  return F;
}

__device__ __forceinline__ void samp_numden(const F9& F, float px, float py,
                                            float qx, float qy, float& num,
                                            float& den, float& dout) {
  float a0 = fmaf(F.f0, px, fmaf(F.f1, py, F.f2));
  float a1 = fmaf(F.f3, px, fmaf(F.f4, py, F.f5));
  float a2 = fmaf(F.f6, px, fmaf(F.f7, py, F.f8));
  float b0 = fmaf(F.f0, qx, fmaf(F.f3, qy, F.f6));
  float b1 = fmaf(F.f1, qx, fmaf(F.f4, qy, F.f7));
  float d = fmaf(qx, a0, fmaf(qy, a1, a2));
  num = d * d;
  den = fmaf(a0, a0, fmaf(a1, a1, fmaf(b0, b0, b1 * b1)));
  dout = d;
}

// predicate num<=den is EXACT (same every round); sqrt(err) = |d|*rsqrt(den).
__device__ __forceinline__ void samp_acc(const F9& F, float px, float py,
                                         float qx, float qy, float& cnt,
                                         float& ss) {
  float num, den, d;
  samp_numden(F, px, py, qx, qy, num, den, d);
  const bool in = (num <= den);
  const float val = fabsf(d) * FAST_RSQF(den);
  cnt += in ? 1.0f : 0.0f;
  ss += in ? val : 0.0f;
}

// ============================================================
// Kernel 1: fit only (no transpose -- consumers read AoS pts directly).
// Block 0 also zeroes acc[64] + ticket + flag (consumed from dispatch 3 on).
// ============================================================
__global__ __launch_bounds__(64, 1) void fit_models(
    const float* __restrict__ pts1, const float* __restrict__ pts2,
    const int* __restrict__ samples, float* __restrict__ models,
    int* __restrict__ uflag, double* __restrict__ acc,
    unsigned int* __restrict__ sync2, int iters) {
  if (blockIdx.x == 0) {
    acc[threadIdx.x] = 0.0;  // 64 threads zero acc[0..63]
    if (threadIdx.x == 0) { sync2[0] = 0u; sync2[1] = 0u; }
  }
  const int it = blockIdx.x * 64 + threadIdx.x;
  if (it >= iters) return;

  int idx[8];
  static_for<8>([&](auto k) { idx[k] = samples[it * 8 + k]; });
  int u = 1;
  static_for<8>([&](auto A) {
    static_for<8>([&](auto B) {
      if constexpr (decltype(B)::value > decltype(A)::value) {
        if (idx[A] == idx[B]) u = 0;
      }
    });
  });
  uflag[it] = u;

  float X1[8], Y1[8], Z1[8], X2[8], Y2[8], Z2[8];
  static_for<8>([&](auto k) {
    const int j = idx[k];
    X1[k] = pts1[3 * j]; Y1[k] = pts1[3 * j + 1]; Z1[k] = pts1[3 * j + 2];
    X2[k] = pts2[3 * j]; Y2[k] = pts2[3 * j + 1]; Z2[k] = pts2[3 * j + 2];
  });
  double sx1 = 0, sy1 = 0, sx2 = 0, sy2 = 0;
  static_for<8>([&](auto k) {
    sx1 += (double)X1[k]; sy1 += (double)Y1[k];
    sx2 += (double)X2[k]; sy2 += (double)Y2[k];
  });
  const double m1x = sx1 / 8.0, m1y = sy1 / 8.0;
  const double m2x = sx2 / 8.0, m2y = sy2 / 8.0;
  double sd1 = 0, sd2 = 0;
  static_for<8>([&](auto k) {
    double dx1 = (double)X1[k] - m1x, dy1 = (double)Y1[k] - m1y;
    double dx2 = (double)X2[k] - m2x, dy2 = (double)Y2[k] - m2y;
    sd1 += sqrt(dx1 * dx1 + dy1 * dy1);
    sd2 += sqrt(dx2 * dx2 + dy2 * dy2);
  });
  const double s1 = sqrt(2.0) / (sd1 / 8.0 + 1e-8);
  const double s2 = sqrt(2.0) / (sd2 / 8.0 + 1e-8);

  double M[45];
  static_for<45>([&](auto r) { M[r] = 0.0; });
  static_for<8>([&](auto k) {
    const double z1 = (double)Z1[k], z2 = (double)Z2[k];
    const double p1x = s1 * ((double)X1[k] - m1x * z1);
    const double p1y = s1 * ((double)Y1[k] - m1y * z1);
    const double p2x = s2 * ((double)X2[k] - m2x * z2);
    const double p2y = s2 * ((double)Y2[k] - m2y * z2);
    const double a[9] = {p2x * p1x, p2x * p1y, p2x * z1,
                         p2y * p1x, p2y * p1y, p2y * z1,
                         z2 * p1x,  z2 * p1y,  z2 * z1};
    ataI<0>(M, a, 1.0);
  });
  solveF(M, s1, m1x, m1y, s2, m2x, m2y, models + (size_t)it * 9);
}

// ============================================================
// Kernel 2: 4 models/block (F in SGPRs), 2 points/iter, AoS point loads
// ============================================================
__global__ __launch_bounds__(256, 4) void sampson_stats4(
    const float* __restrict__ pts1, const float* __restrict__ pts2,
    const float* __restrict__ models, float* __restrict__ ml,
    float* __restrict__ ssum, int N, int iters) {
  const int m0 = blockIdx.x * 4;
  const int c0 = min(m0 + 0, iters - 1), c1 = min(m0 + 1, iters - 1);
  const int c2 = min(m0 + 2, iters - 1), c3 = min(m0 + 3, iters - 1);
  const F9 Fa = loadF(models + (size_t)c0 * 9);
  const F9 Fb = loadF(models + (size_t)c1 * 9);
  const F9 Fc = loadF(models + (size_t)c2 * 9);
  const F9 Fd = loadF(models + (size_t)c3 * 9);
  float ca = 0, cb = 0, cc = 0, cd = 0;
  float sa = 0, sb = 0, sc_ = 0, sd = 0;
  const int NP = N & ~511;
  for (int i = threadIdx.x; i < NP; i += 512) {
    const int j = i + 256;
    const float pxA = pts1[3 * i], pyA = pts1[3 * i + 1];
    const float qxA = pts2[3 * i], qyA = pts2[3 * i + 1];
    const float pxB = pts1[3 * j], pyB = pts1[3 * j + 1];
    const float qxB = pts2[3 * j], qyB = pts2[3 * j + 1];
    samp_acc(Fa, pxA, pyA, qxA, qyA, ca, sa);
    samp_acc(Fb, pxA, pyA, qxA, qyA, cb, sb);
    samp_acc(Fc, pxA, pyA, qxA, qyA, cc, sc_);
    samp_acc(Fd, pxA, pyA, qxA, qyA, cd, sd);
    samp_acc(Fa, pxB, pyB, qxB, qyB, ca, sa);
    samp_acc(Fb, pxB, pyB, qxB, qyB, cb, sb);
    samp_acc(Fc, pxB, pyB, qxB, qyB, cc, sc_);
    samp_acc(Fd, pxB, pyB, qxB, qyB, cd, sd);
  }
  for (int i = NP + threadIdx.x; i < N; i += 256) {
    const float px = pts1[3 * i], py = pts1[3 * i + 1];
    const float qx = pts2[3 * i], qy = pts2[3 * i + 1];
    samp_acc(Fa, px, py, qx, qy, ca, sa);
    samp_acc(Fb, px, py, qx, qy, cb, sb);
    samp_acc(Fc, px, py, qx, qy, cc, sc_);
    samp_acc(Fd, px, py, qx, qy, cd, sd);
  }
  __shared__ float shc[4][4], shs[4][4];
  const int lane = threadIdx.x & 63, wv = threadIdx.x >> 6;
  float c4[4] = {ca, cb, cc, cd};
  float s4[4] = {sa, sb, sc_, sd};
  static_for<4>([&](auto m) {
    float c = c4[m], s = s4[m];
#pragma unroll
    for (int o = 32; o > 0; o >>= 1) {
      c += __shfl_down(c, o);
      s += __shfl_down(s, o);
    }
    if (lane == 0) { shc[wv][m] = c; shs[wv][m] = s; }
  });
  __syncthreads();
  if (threadIdx.x < 4 && m0 + threadIdx.x < iters) {
    const int m = threadIdx.x;
    ml[m0 + m] = shc[0][m] + shc[1][m] + shc[2][m] + shc[3][m];
    ssum[m0 + m] = shs[0][m] + shs[1][m] + shs[2][m] + shs[3][m];
  }
}

// ============================================================
// Kernel 3: select (redundant/block) + mask + mean-sums + in-dispatch
// soft barrier + dist-sums + unscaled AtA. 64 blocks <= 256 CUs at
// launch_bounds(256,1) -> all blocks guaranteed co-resident, so the
// spin on `flag` cannot deadlock. Mask bits stay in registers across
// the barrier (pass1 and pass2 cover the same i = blockIdx*256+tid).
// acc: [0]=sw [1..4]=coord sums [5]=sd1 [6]=sd2 [7..51]=AtA
//      [52..56]=means broadcast (M1X,M1Y,M2X,M2Y unused slot)
// sync2: [0]=ticket [1]=flag
// ============================================================
__global__ __launch_bounds__(256, 1) void selmask_final(
    const float* __restrict__ pts1, const float* __restrict__ pts2,
    const float* __restrict__ models, const float* __restrict__ ml,
    const float* __restrict__ ssum, const int* __restrict__ uniq,
    float* __restrict__ outmask, double* __restrict__ acc,
    unsigned int* __restrict__ sync2, int N, int iters, int NB) {
  const int tid = threadIdx.x;
  __shared__ float ra[256], rb[256];
  __shared__ int rid[256];
  // ---- phase A: redundant select (R10-proven; inputs from prior dispatches)
  float mlmax = 0.f, mnmax = -INFINITY;
  for (int i = tid; i < iters; i += 256) {
    if (uniq[i]) {
      float m = ml[i];
      mlmax = fmaxf(mlmax, m);
      float mean = (ssum[i] + 1e-8f) / (m + 1e-8f);
      mnmax = fmaxf(mnmax, mean);
    }
  }
  ra[tid] = mlmax;
  rb[tid] = mnmax;
  __syncthreads();
  for (int s = 128; s > 0; s >>= 1) {
    if (tid < s) {
      ra[tid] = fmaxf(ra[tid], ra[tid + s]);
      rb[tid] = fmaxf(rb[tid], rb[tid + s]);
    }
    __syncthreads();
  }
  const float MLMAX = ra[0];
  const float MNMAX = rb[0];
  __syncthreads();
  float bsc = -INFINITY;
  int bid = 0x7FFFFFFF;
  for (int i = tid; i < iters; i += 256) {
    float sc = -INFINITY;
    float m = ml[i];
    float mean = (ssum[i] + 1e-8f) / (m + 1e-8f);
    if (uniq[i]) sc = 0.5f * (m / MLMAX) + 0.5f * (1.0f - mean / MNMAX);
    if (sc > bsc || (sc == bsc && i < bid)) { bsc = sc; bid = i; }
  }
  ra[tid] = bsc;
  rid[tid] = bid;
  __syncthreads();
  for (int s = 128; s > 0; s >>= 1) {
    if (tid < s) {
      if (ra[tid + s] > ra[tid] ||
          (ra[tid + s] == ra[tid] && rid[tid + s] < rid[tid])) {
        ra[tid] = ra[tid + s];
        rid[tid] = rid[tid + s];
      }
    }
    __syncthreads();
  }
  const int best = rid[0];

  // ---- phase B: mask + mean-sums; keep point + mask bit in registers
  const int i = blockIdx.x * 256 + tid;
  float px = 0.f, py = 0.f, qx = 0.f, qy = 0.f;
  bool in = false;
  if (i < N) {
    const F9 F = loadF(models + (size_t)best * 9);
    px = pts1[3 * i]; py = pts1[3 * i + 1];
    qx = pts2[3 * i]; qy = pts2[3 * i + 1];
    float num, den, dd;
    samp_numden(F, px, py, qx, qy, num, den, dd);
    in = (num <= den);  // same predicate as sampson_stats4
    outmask[i] = in ? 1.0f : 0.0f;
  }
  {
    double w = in ? 1.0 : 0.0;
    double a = in ? (double)px : 0.0, b = in ? (double)py : 0.0;
    double c = in ? (double)qx : 0.0, d = in ? (double)qy : 0.0;
#pragma unroll
    for (int o = 32; o > 0; o >>= 1) {
      w += __shfl_down(w, o); a += __shfl_down(a, o); b += __shfl_down(b, o);
      c += __shfl_down(c, o); d += __shfl_down(d, o);
    }
    if ((tid & 63) == 0) {
      atomicAdd(&acc[0], w); atomicAdd(&acc[1], a); atomicAdd(&acc[2], b);
      atomicAdd(&acc[3], c); atomicAdd(&acc[4], d);
    }
  }
  // ---- soft grid barrier: last block computes means, others spin
  __syncthreads();
  __shared__ int amLast;
  if (tid == 0) {
    __threadfence();
    amLast = (atomicAdd(&sync2[0], 1u) == (unsigned int)(NB - 1)) ? 1 : 0;
  }
  __syncthreads();
  if (amLast && tid == 0) {
    const double WS = atomicAdd(&acc[0], 0.0);
    acc[52] = atomicAdd(&acc[1], 0.0) / WS;  // M1X
    acc[53] = atomicAdd(&acc[2], 0.0) / WS;  // M1Y
    acc[54] = atomicAdd(&acc[3], 0.0) / WS;  // M2X
    acc[55] = atomicAdd(&acc[4], 0.0) / WS;  // M2Y
    __threadfence();
    atomicExch(&sync2[1], 1u);
  }
  __shared__ double smean[4];
  if (tid == 0) {
    while (atomicAdd(&sync2[1], 0u) == 0u) {
      __builtin_amdgcn_s_sleep(1);
    }
    __threadfence();
    smean[0] = atomicAdd(&acc[52], 0.0);
    smean[1] = atomicAdd(&acc[53], 0.0);
    smean[2] = atomicAdd(&acc[54], 0.0);
    smean[3] = atomicAdd(&acc[55], 0.0);
  }
  __syncthreads();
  const double M1X = smean[0], M1Y = smean[1];
  const double M2X = smean[2], M2Y = smean[3];

  // ---- phase C: dist-sums + UNSCALED AtA (same point, mask in register)
  double sd1 = 0, sd2 = 0;
  double A[45];
  static_for<45>([&](auto r) { A[r] = 0.0; });
  if (in) {
    const double v0 = (double)px - M1X, v1 = (double)py - M1Y;
    const double u0 = (double)qx - M2X, u1 = (double)qy - M2Y;
    sd1 = sqrt(v0 * v0 + v1 * v1);
    sd2 = sqrt(u0 * u0 + u1 * u1);
    const double a[9] = {u0 * v0, u0 * v1, u0,
                         u1 * v0, u1 * v1, u1,
                         v0,      v1,      1.0};
    ataI<0>(A, a, 1.0);
  }
  const int lane = tid & 63;
  {
    double t1 = sd1, t2 = sd2;
#pragma unroll
    for (int o = 32; o > 0; o >>= 1) {
      t1 += __shfl_down(t1, o);
      t2 += __shfl_down(t2, o);
    }
    if (lane == 0) {
      atomicAdd(&acc[5], t1);
      atomicAdd(&acc[6], t2);
    }
  }
  static_for<45>([&](auto r) {
    double v = A[r];
#pragma unroll
    for (int o = 32; o > 0; o >>= 1) v += __shfl_down(v, o);
    if (lane == 0) atomicAdd(&acc[7 + r], v);
  });
}

// ============================================================
// Kernel 4: solve (own kernel -> registerizes; R7/R10 evidence).
// Applies D*M*D scaling then the rank-2 + denormalize pipeline.
// ============================================================
__global__ __launch_bounds__(64, 1) void ff_solve(const double* __restrict__ acc,
                                                  float* __restrict__ outF) {
  if (threadIdx.x != 0 || blockIdx.x != 0) return;
  const double WS = acc[0];
  const double M1X = acc[1] / WS, M1Y = acc[2] / WS;
  const double M2X = acc[3] / WS, M2Y = acc[4] / WS;
  const double S1 = sqrt(2.0) / (acc[5] / WS + 1e-8);
  const double S2 = sqrt(2.0) / (acc[6] / WS + 1e-8);
  double M[45];
  static_for<45>([&](auto r) { M[r] = acc[7 + r]; });
  // apply D * M * D, D_(3i+j) = S2^[i<2] * S1^[j<2]
  static_for<9>([&](auto R) {
    static_for<9>([&](auto C) {
      constexpr int r = decltype(R)::value;
      constexpr int c = decltype(C)::value;
      if constexpr (c <= r) {
        const double sr = ((r / 3) < 2 ? S2 : 1.0) * ((r % 3) < 2 ? S1 : 1.0);
        const double sc = ((c / 3) < 2 ? S2 : 1.0) * ((c % 3) < 2 ? S1 : 1.0);
        M[PIX(r, c)] *= sr * sc;
      }
    });
  });
  solveF(M, S1, M1X, M1Y, S2, M2X, M2Y, outF);
}

// ============================================================
// Host launcher — 4 dispatches
// ============================================================
extern "C" void kernel_launch(void* const* d_in, const int* in_sizes, int n_in,
                              void* d_out, int out_size, void* d_ws, size_t ws_size,
                              hipStream_t stream) {
  const float* pts1 = (const float*)d_in[0];
  const float* pts2 = (const float*)d_in[1];
  const int* samples = (const int*)d_in[2];
  const int N = in_sizes[0] / 3;      // 16384
  const int iters = in_sizes[2] / 8;  // 4096

  // workspace layout (16B-aligned start)
  double* acc = (double*)d_ws;                        // 64 doubles
  unsigned int* sync2 = (unsigned int*)(acc + 64);    // ticket, flag (+pad)
  float* models = (float*)(sync2 + 4);                // iters*9
  float* ml = models + (size_t)iters * 9;             // iters
  float* ssum = ml + iters;                           // iters
  int* uniq = (int*)(ssum + iters);                   // iters

  float* outF = (float*)d_out;  // 9 floats (Mbest)
  float* outmask = outF + 9;    // N floats (0/1)

  const int FB = (iters + 63) / 64;
  const int NB = (N + 255) / 256;  // 64 blocks -> co-resident (<= 256 CUs)
  fit_models<<<FB, 64, 0, stream>>>(pts1, pts2, samples, models, uniq, acc,
                                    sync2, iters);
  sampson_stats4<<<(iters + 3) / 4, 256, 0, stream>>>(pts1, pts2, models, ml,
                                                      ssum, N, iters);
  selmask_final<<<NB, 256, 0, stream>>>(pts1, pts2, models, ml, ssum, uniq,
                                        outmask, acc, sync2, N, iters, NB);
  ff_solve<<<1, 64, 0, stream>>>(acc, outF);
}

// Round 12
// 179.216 us; speedup vs baseline: 1.1889x; 1.1889x over previous
//
#include <hip/hip_runtime.h>
#include <math.h>
#include <type_traits>
#include <utility>

#if defined(__has_builtin)
#if __has_builtin(__builtin_amdgcn_rcpf)
#define FAST_RCPF(x) __builtin_amdgcn_rcpf(x)
#endif
#if __has_builtin(__builtin_amdgcn_rsqf)
#define FAST_RSQF(x) __builtin_amdgcn_rsqf(x)
#endif
#endif
#ifndef FAST_RCPF
#define FAST_RCPF(x) (1.0f / (x))
#endif
#ifndef FAST_RSQF
#define FAST_RSQF(x) (1.0f / sqrtf(x))
#endif

// packed lower-tri index (constexpr -> folds in templates)
__host__ __device__ constexpr int PIX(int i, int j) { return i * (i + 1) / 2 + j; }

// ============================================================
// static_for: source-level unrolling. RULE (R6/R7): SROA runs BEFORE loop
// unrolling and never re-runs -> template recursion emits literal-constant
// indices so the first SROA pass promotes allocas to registers.
// RULE (R9, re-confirmed R11): any kernel holding the 45-double accumulator
// must be a DEDICATED simple kernel -- adding phases (select/barrier/LDS)
// drops the allocator below the registerization threshold (R11: VGPR=52,
// 92us). Streaming-AtA alone (R10 ff_p23) registerizes fine.
// ============================================================
template <int N, int I = 0, typename F>
__device__ __forceinline__ void static_for(F&& f) {
  if constexpr (I < N) {
    f(std::integral_constant<int, I>{});
    static_for<N, I + 1>(static_cast<F&&>(f));
  }
}

// ---------- 9x9 packed Cholesky, template-indexed ----------
template <int I, int J, int K>
__device__ __forceinline__ double csub9(const double* M, double s) {
  if constexpr (K >= J) return s;
  else return csub9<I, J, K + 1>(M, s - M[PIX(I, K)] * M[PIX(J, K)]);
}
template <int I, int J>
__device__ __forceinline__ void cholJ(double* M) {
  if constexpr (J <= I) {
    double s = csub9<I, J, 0>(M, M[PIX(I, J)]);
    if constexpr (J == I)
      M[PIX(I, I)] = sqrt(fmax(s, 1e-300));
    else
      M[PIX(I, J)] = s / M[PIX(J, J)];
    cholJ<I, J + 1>(M);
  }
}
template <int I>
__device__ __forceinline__ void cholI(double* M) {
  if constexpr (I < 9) {
    cholJ<I, 0>(M);
    cholI<I + 1>(M);
  }
}

// ---------- forward/backward substitution, template-indexed ----------
template <int I, int K>
__device__ __forceinline__ double fsub9(const double* L, const double* x, double s) {
  if constexpr (K >= I) return s;
  else return fsub9<I, K + 1>(L, x, s - L[PIX(I, K)] * x[K]);
}
template <int I>
__device__ __forceinline__ void fwd9(const double* L, double* x) {
  if constexpr (I < 9) {
    x[I] = fsub9<I, 0>(L, x, x[I]) / L[PIX(I, I)];
    fwd9<I + 1>(L, x);
  }
}
template <int I, int K>
__device__ __forceinline__ double bsub9(const double* L, const double* x, double s) {
  if constexpr (K >= 9) return s;
  else return bsub9<I, K + 1>(L, x, s - L[PIX(K, I)] * x[K]);
}
template <int I>
__device__ __forceinline__ void bwd9(const double* L, double* x) {
  if constexpr (I >= 0) {
    x[I] = bsub9<I, I + 1>(L, x, x[I]) / L[PIX(I, I)];
    bwd9<I - 1>(L, x);
  }
}

// ---------- AtA rank-1 update (45 packed entries), template-indexed ----------
template <int I, int J>
__device__ __forceinline__ void ataIJ(double* M, const double (&a)[9], double w) {
  if constexpr (J <= I) {
    M[PIX(I, J)] += w * a[I] * a[J];
    ataIJ<I, J + 1>(M, a, w);
  }
}
template <int I>
__device__ __forceinline__ void ataI(double* M, const double (&a)[9], double w) {
  if constexpr (I < 9) {
    ataIJ<I, 0>(M, a, w);
    ataI<I + 1>(M, a, w);
  }
}

// ---------- 3x3 Jacobi rotation on named scalars (no arrays at all) ----------
#define JROT(P, Q)                                                              \
  {                                                                             \
    double apq = a##P##Q;                                                       \
    if (fabs(apq) >= 1e-300) {                                                  \
      double tau = (a##Q##Q - a##P##P) / (2.0 * apq);                           \
      double t = ((tau >= 0.0) ? 1.0 : -1.0) / (fabs(tau) + sqrt(1.0 + tau * tau)); \
      double c = 1.0 / sqrt(1.0 + t * t);                                       \
      double s = t * c;                                                         \
      double t0p = a0##P, t0q = a0##Q;                                          \
      a0##P = c * t0p - s * t0q; a0##Q = s * t0p + c * t0q;                     \
      double t1p = a1##P, t1q = a1##Q;                                          \
      a1##P = c * t1p - s * t1q; a1##Q = s * t1p + c * t1q;                     \
      double t2p = a2##P, t2q = a2##Q;                                          \
      a2##P = c * t2p - s * t2q; a2##Q = s * t2p + c * t2q;                     \
      double rp0 = a##P##0, rq0 = a##Q##0;                                      \
      a##P##0 = c * rp0 - s * rq0; a##Q##0 = s * rp0 + c * rq0;                 \
      double rp1 = a##P##1, rq1 = a##Q##1;                                      \
      a##P##1 = c * rp1 - s * rq1; a##Q##1 = s * rp1 + c * rq1;                 \
      double rp2 = a##P##2, rq2 = a##Q##2;                                      \
      a##P##2 = c * rp2 - s * rq2; a##Q##2 = s * rp2 + c * rq2;                 \
      double u0p = V0##P, u0q = V0##Q;                                          \
      V0##P = c * u0p - s * u0q; V0##Q = s * u0p + c * u0q;                     \
      double u1p = V1##P, u1q = V1##Q;                                          \
      V1##P = c * u1p - s * u1q; V1##Q = s * u1p + c * u1q;                     \
      double u2p = V2##P, u2q = V2##Q;                                          \
      V2##P = c * u2p - s * u2q; V2##Q = s * u2p + c * u2q;                     \
    }                                                                           \
  }

// ---------- full solver: null vec of AtA -> rank-2 -> denormalize ----------
__device__ __forceinline__ void solveF(double* M, double s1, double m1x, double m1y,
                                       double s2, double m2x, double m2y,
                                       float* out) {
  double tr = M[0] + M[2] + M[5] + M[9] + M[14] + M[20] + M[27] + M[35] + M[44];
  double shift = 1e-12 * tr;
  M[0] += shift; M[2] += shift; M[5] += shift; M[9] += shift; M[14] += shift;
  M[20] += shift; M[27] += shift; M[35] += shift; M[44] += shift;
  cholI<0>(M);
  double x[9];
  static_for<9>([&](auto i) { x[i] = 1.0; });
  static_for<3>([&](auto) {
    fwd9<0>(M, x);
    bwd9<8>(M, x);
    double n = 0.0;
    static_for<9>([&](auto i) { n += x[i] * x[i]; });
    n = 1.0 / sqrt(n);
    static_for<9>([&](auto i) { x[i] *= n; });
  });
  const double g00 = x[0] * x[0] + x[3] * x[3] + x[6] * x[6];
  const double g01 = x[0] * x[1] + x[3] * x[4] + x[6] * x[7];
  const double g02 = x[0] * x[2] + x[3] * x[5] + x[6] * x[8];
  const double g11 = x[1] * x[1] + x[4] * x[4] + x[7] * x[7];
  const double g12 = x[1] * x[2] + x[4] * x[5] + x[7] * x[8];
  const double g22 = x[2] * x[2] + x[5] * x[5] + x[8] * x[8];
  double a00 = g00, a01 = g01, a02 = g02;
  double a10 = g01, a11 = g11, a12 = g12;
  double a20 = g02, a21 = g12, a22 = g22;
  double V00 = 1, V01 = 0, V02 = 0;
  double V10 = 0, V11 = 1, V12 = 0;
  double V20 = 0, V21 = 0, V22 = 1;
  for (int sweep = 0; sweep < 6; ++sweep) {
    JROT(0, 1);
    JROT(0, 2);
    JROT(1, 2);
  }
  double mv = a00, v0 = V00, v1 = V10, v2 = V20;
  if (a11 < mv) { mv = a11; v0 = V01; v1 = V11; v2 = V21; }
  if (a22 < mv) { mv = a22; v0 = V02; v1 = V12; v2 = V22; }
  const double fv0 = x[0] * v0 + x[1] * v1 + x[2] * v2;
  const double fv1 = x[3] * v0 + x[4] * v1 + x[5] * v2;
  const double fv2 = x[6] * v0 + x[7] * v1 + x[8] * v2;
  const double F200 = x[0] - fv0 * v0, F201 = x[1] - fv0 * v1, F202 = x[2] - fv0 * v2;
  const double F210 = x[3] - fv1 * v0, F211 = x[4] - fv1 * v1, F212 = x[5] - fv1 * v2;
  const double F220 = x[6] - fv2 * v0, F221 = x[7] - fv2 * v1, F222 = x[8] - fv2 * v2;
  const double R00 = s2 * F200, R01 = s2 * F201, R02 = s2 * F202;
  const double R10 = s2 * F210, R11 = s2 * F211, R12 = s2 * F212;
  const double R20 = -s2 * m2x * F200 - s2 * m2y * F210 + F220;
  const double R21 = -s2 * m2x * F201 - s2 * m2y * F211 + F221;
  const double R22 = -s2 * m2x * F202 - s2 * m2y * F212 + F222;
  const double Ff00 = s1 * R00, Ff01 = s1 * R01;
  const double Ff02 = -s1 * m1x * R00 - s1 * m1y * R01 + R02;
  const double Ff10 = s1 * R10, Ff11 = s1 * R11;
  const double Ff12 = -s1 * m1x * R10 - s1 * m1y * R11 + R12;
  const double Ff20 = s1 * R20, Ff21 = s1 * R21;
  const double Ff22 = -s1 * m1x * R20 - s1 * m1y * R21 + R22;
  const double inv = 1.0 / Ff22;
  out[0] = (float)(Ff00 * inv); out[1] = (float)(Ff01 * inv); out[2] = (float)(Ff02 * inv);
  out[3] = (float)(Ff10 * inv); out[4] = (float)(Ff11 * inv); out[5] = (float)(Ff12 * inv);
  out[6] = (float)(Ff20 * inv); out[7] = (float)(Ff21 * inv); out[8] = (float)(Ff22 * inv);
}

// ============================================================
// Sampson terms (z==1.0 exactly; elision is bit-identical)
// ============================================================
struct F9 {
  float f0, f1, f2, f3, f4, f5, f6, f7, f8;
};

__device__ __forceinline__ F9 loadF(const float* __restrict__ p) {
  F9 F;
  F.f0 = p[0]; F.f1 = p[1]; F.f2 = p[2];
  F.f3 = p[3]; F.f4 = p[4]; F.f5 = p[5];
  F.f6 = p[6]; F.f7 = p[7]; F.f8 = p[8];
  return F;
}

__device__ __forceinline__ void samp_numden(const F9& F, float px, float py,
                                            float qx, float qy, float& num,
                                            float& den, float& dout) {
  float a0 = fmaf(F.f0, px, fmaf(F.f1, py, F.f2));
  float a1 = fmaf(F.f3, px, fmaf(F.f4, py, F.f5));
  float a2 = fmaf(F.f6, px, fmaf(F.f7, py, F.f8));
  float b0 = fmaf(F.f0, qx, fmaf(F.f3, qy, F.f6));
  float b1 = fmaf(F.f1, qx, fmaf(F.f4, qy, F.f7));
  float d = fmaf(qx, a0, fmaf(qy, a1, a2));
  num = d * d;
  den = fmaf(a0, a0, fmaf(a1, a1, fmaf(b0, b0, b1 * b1)));
  dout = d;
}

// predicate num<=den is EXACT (same every round); sqrt(err) = |d|*rsqrt(den).
__device__ __forceinline__ void samp_acc(const F9& F, float px, float py,
                                         float qx, float qy, float& cnt,
                                         float& ss) {
  float num, den, d;
  samp_numden(F, px, py, qx, qy, num, den, d);
  const bool in = (num <= den);
  const float val = fabsf(d) * FAST_RSQF(den);
  cnt += in ? 1.0f : 0.0f;
  ss += in ? val : 0.0f;
}

// ============================================================
// Kernel 1: transpose blocks [0,TB) (float2 x,y only -- z==1 never read)
//           + fit blocks [TB,..) (1 thread = 1 model).
// Block 0 also zeroes acc[52].
// ============================================================
__global__ __launch_bounds__(256, 1) void prep_and_fit(
    const float* __restrict__ pts1, const float* __restrict__ pts2,
    const int* __restrict__ samples, float2* __restrict__ P1,
    float2* __restrict__ P2, float* __restrict__ models,
    int* __restrict__ uflag, double* __restrict__ acc, int N, int iters,
    int TB) {
  if ((int)blockIdx.x < TB) {
    if (blockIdx.x == 0 && threadIdx.x < 52) acc[threadIdx.x] = 0.0;
    const int i = blockIdx.x * 256 + threadIdx.x;
    if (i < N) {
      P1[i] = make_float2(pts1[3 * i], pts1[3 * i + 1]);
      P2[i] = make_float2(pts2[3 * i], pts2[3 * i + 1]);
    }
    return;
  }
  if (threadIdx.x >= 64) return;
  const int it = (blockIdx.x - TB) * 64 + threadIdx.x;
  if (it >= iters) return;

  int idx[8];
  static_for<8>([&](auto k) { idx[k] = samples[it * 8 + k]; });
  int u = 1;
  static_for<8>([&](auto A) {
    static_for<8>([&](auto B) {
      if constexpr (decltype(B)::value > decltype(A)::value) {
        if (idx[A] == idx[B]) u = 0;
      }
    });
  });
  uflag[it] = u;

  float X1[8], Y1[8], Z1[8], X2[8], Y2[8], Z2[8];
  static_for<8>([&](auto k) {
    const int j = idx[k];
    X1[k] = pts1[3 * j]; Y1[k] = pts1[3 * j + 1]; Z1[k] = pts1[3 * j + 2];
    X2[k] = pts2[3 * j]; Y2[k] = pts2[3 * j + 1]; Z2[k] = pts2[3 * j + 2];
  });
  double sx1 = 0, sy1 = 0, sx2 = 0, sy2 = 0;
  static_for<8>([&](auto k) {
    sx1 += (double)X1[k]; sy1 += (double)Y1[k];
    sx2 += (double)X2[k]; sy2 += (double)Y2[k];
  });
  const double m1x = sx1 / 8.0, m1y = sy1 / 8.0;
  const double m2x = sx2 / 8.0, m2y = sy2 / 8.0;
  double sd1 = 0, sd2 = 0;
  static_for<8>([&](auto k) {
    double dx1 = (double)X1[k] - m1x, dy1 = (double)Y1[k] - m1y;
    double dx2 = (double)X2[k] - m2x, dy2 = (double)Y2[k] - m2y;
    sd1 += sqrt(dx1 * dx1 + dy1 * dy1);
    sd2 += sqrt(dx2 * dx2 + dy2 * dy2);
  });
  const double s1 = sqrt(2.0) / (sd1 / 8.0 + 1e-8);
  const double s2 = sqrt(2.0) / (sd2 / 8.0 + 1e-8);

  double M[45];
  static_for<45>([&](auto r) { M[r] = 0.0; });
  static_for<8>([&](auto k) {
    const double z1 = (double)Z1[k], z2 = (double)Z2[k];
    const double p1x = s1 * ((double)X1[k] - m1x * z1);
    const double p1y = s1 * ((double)Y1[k] - m1y * z1);
    const double p2x = s2 * ((double)X2[k] - m2x * z2);
    const double p2y = s2 * ((double)Y2[k] - m2y * z2);
    const double a[9] = {p2x * p1x, p2x * p1y, p2x * z1,
                         p2y * p1x, p2y * p1y, p2y * z1,
                         z2 * p1x,  z2 * p1y,  z2 * z1};
    ataI<0>(M, a, 1.0);
  });
  solveF(M, s1, m1x, m1y, s2, m2x, m2y, models + (size_t)it * 9);
}

// ============================================================
// Kernel 2: 4 models/block (F in SGPRs), 2 points/iter, float2 loads
// ============================================================
__global__ __launch_bounds__(256, 4) void sampson_stats4(
    const float2* __restrict__ P1, const float2* __restrict__ P2,
    const float* __restrict__ models, float* __restrict__ ml,
    float* __restrict__ ssum, int N, int iters) {
  const int m0 = blockIdx.x * 4;
  const int c0 = min(m0 + 0, iters - 1), c1 = min(m0 + 1, iters - 1);
  const int c2 = min(m0 + 2, iters - 1), c3 = min(m0 + 3, iters - 1);
  const F9 Fa = loadF(models + (size_t)c0 * 9);
  const F9 Fb = loadF(models + (size_t)c1 * 9);
  const F9 Fc = loadF(models + (size_t)c2 * 9);
  const F9 Fd = loadF(models + (size_t)c3 * 9);
  float ca = 0, cb = 0, cc = 0, cd = 0;
  float sa = 0, sb = 0, sc_ = 0, sd = 0;
  const int NP = N & ~511;
  for (int i = threadIdx.x; i < NP; i += 512) {
    const float2 pA = P1[i];
    const float2 qA = P2[i];
    const float2 pB = P1[i + 256];
    const float2 qB = P2[i + 256];
    samp_acc(Fa, pA.x, pA.y, qA.x, qA.y, ca, sa);
    samp_acc(Fb, pA.x, pA.y, qA.x, qA.y, cb, sb);
    samp_acc(Fc, pA.x, pA.y, qA.x, qA.y, cc, sc_);
    samp_acc(Fd, pA.x, pA.y, qA.x, qA.y, cd, sd);
    samp_acc(Fa, pB.x, pB.y, qB.x, qB.y, ca, sa);
    samp_acc(Fb, pB.x, pB.y, qB.x, qB.y, cb, sb);
    samp_acc(Fc, pB.x, pB.y, qB.x, qB.y, cc, sc_);
    samp_acc(Fd, pB.x, pB.y, qB.x, qB.y, cd, sd);
  }
  for (int i = NP + threadIdx.x; i < N; i += 256) {
    const float2 p = P1[i];
    const float2 q = P2[i];
    samp_acc(Fa, p.x, p.y, q.x, q.y, ca, sa);
    samp_acc(Fb, p.x, p.y, q.x, q.y, cb, sb);
    samp_acc(Fc, p.x, p.y, q.x, q.y, cc, sc_);
    samp_acc(Fd, p.x, p.y, q.x, q.y, cd, sd);
  }
  __shared__ float shc[4][4], shs[4][4];
  const int lane = threadIdx.x & 63, wv = threadIdx.x >> 6;
  float c4[4] = {ca, cb, cc, cd};
  float s4[4] = {sa, sb, sc_, sd};
  static_for<4>([&](auto m) {
    float c = c4[m], s = s4[m];
#pragma unroll
    for (int o = 32; o > 0; o >>= 1) {
      c += __shfl_down(c, o);
      s += __shfl_down(s, o);
    }
    if (lane == 0) { shc[wv][m] = c; shs[wv][m] = s; }
  });
  __syncthreads();
  if (threadIdx.x < 4 && m0 + threadIdx.x < iters) {
    const int m = threadIdx.x;
    ml[m0 + m] = shc[0][m] + shc[1][m] + shc[2][m] + shc[3][m];
    ssum[m0 + m] = shs[0][m] + shs[1][m] + shs[2][m] + shs[3][m];
  }
}

// ============================================================
// Kernel 3: fused select_best + mask + mean-sums (R10-proven shape).
// acc: [0]=sw [1..4]=coord sums [5]=sd1 [6]=sd2 [7..51]=AtA
// ============================================================
__global__ __launch_bounds__(256) void selmask_p1(
    const float2* __restrict__ P1, const float2* __restrict__ P2,
    const float* __restrict__ models, const float* __restrict__ ml,
    const float* __restrict__ ssum, const int* __restrict__ uniq,
    float* __restrict__ outmask, double* __restrict__ acc, int N, int iters) {
  const int tid = threadIdx.x;
  __shared__ float ra[256], rb[256];
  __shared__ int rid[256];
  float mlmax = 0.f, mnmax = -INFINITY;
  for (int i = tid; i < iters; i += 256) {
    if (uniq[i]) {
      float m = ml[i];
      mlmax = fmaxf(mlmax, m);
      float mean = (ssum[i] + 1e-8f) / (m + 1e-8f);
      mnmax = fmaxf(mnmax, mean);
    }
  }
  ra[tid] = mlmax;
  rb[tid] = mnmax;
  __syncthreads();
  for (int s = 128; s > 0; s >>= 1) {
    if (tid < s) {
      ra[tid] = fmaxf(ra[tid], ra[tid + s]);
      rb[tid] = fmaxf(rb[tid], rb[tid + s]);
    }
    __syncthreads();
  }
  const float MLMAX = ra[0];
  const float MNMAX = rb[0];
  __syncthreads();
  float bsc = -INFINITY;
  int bid = 0x7FFFFFFF;
  for (int i = tid; i < iters; i += 256) {
    float sc = -INFINITY;
    float m = ml[i];
    float mean = (ssum[i] + 1e-8f) / (m + 1e-8f);
    if (uniq[i]) sc = 0.5f * (m / MLMAX) + 0.5f * (1.0f - mean / MNMAX);
    if (sc > bsc || (sc == bsc && i < bid)) { bsc = sc; bid = i; }
  }
  ra[tid] = bsc;
  rid[tid] = bid;
  __syncthreads();
  for (int s = 128; s > 0; s >>= 1) {
    if (tid < s) {
      if (ra[tid + s] > ra[tid] ||
          (ra[tid + s] == ra[tid] && rid[tid + s] < rid[tid])) {
        ra[tid] = ra[tid + s];
        rid[tid] = rid[tid + s];
      }
    }
    __syncthreads();
  }
  const int best = rid[0];

  // ---- mask write + weighted sums for means
  const int i = blockIdx.x * 256 + tid;
  double w = 0, a = 0, b = 0, c = 0, d = 0;
  if (i < N) {
    const F9 F = loadF(models + (size_t)best * 9);
    const float2 p = P1[i];
    const float2 q = P2[i];
    float num, den, dd;
    samp_numden(F, p.x, p.y, q.x, q.y, num, den, dd);
    const bool in = (num <= den);  // same predicate as sampson_stats4
    float m = in ? 1.0f : 0.0f;
    outmask[i] = m;
    w = (double)m;
    a = w * (double)p.x;
    b = w * (double)p.y;
    c = w * (double)q.x;
    d = w * (double)q.y;
  }
#pragma unroll
  for (int o = 32; o > 0; o >>= 1) {
    w += __shfl_down(w, o); a += __shfl_down(a, o); b += __shfl_down(b, o);
    c += __shfl_down(c, o); d += __shfl_down(d, o);
  }
  if ((tid & 63) == 0) {
    atomicAdd(&acc[0], w); atomicAdd(&acc[1], a); atomicAdd(&acc[2], b);
    atomicAdd(&acc[3], c); atomicAdd(&acc[4], d);
  }
}

// ============================================================
// Kernel 4: DEDICATED one-pass dist-sums + UNSCALED AtA (streaming only;
// solver deliberately elsewhere -- R9/R11 lesson).
// ============================================================
__global__ __launch_bounds__(256, 1) void ff_p23(
    const float* __restrict__ mask, const float2* __restrict__ P1,
    const float2* __restrict__ P2, double* __restrict__ acc, int N) {
  const double WS = acc[0];
  const double M1X = acc[1] / WS, M1Y = acc[2] / WS;
  const double M2X = acc[3] / WS, M2Y = acc[4] / WS;
  double sd1 = 0, sd2 = 0;
  double A[45];
  static_for<45>([&](auto r) { A[r] = 0.0; });
#pragma unroll
  for (int k = 0; k < 4; ++k) {
    const int i = blockIdx.x * 1024 + k * 256 + threadIdx.x;
    if (i < N) {
      const double w = (double)mask[i];
      if (w != 0.0) {
        const float2 p = P1[i];
        const float2 q = P2[i];
        const double v0 = (double)p.x - M1X, v1 = (double)p.y - M1Y;
        const double u0 = (double)q.x - M2X, u1 = (double)q.y - M2Y;
        sd1 += sqrt(v0 * v0 + v1 * v1);  // w == 1
        sd2 += sqrt(u0 * u0 + u1 * u1);
        const double a[9] = {u0 * v0, u0 * v1, u0,
                             u1 * v0, u1 * v1, u1,
                             v0,      v1,      1.0};
        ataI<0>(A, a, 1.0);
      }
    }
  }
  const int lane = threadIdx.x & 63;
  {
    double t1 = sd1, t2 = sd2;
#pragma unroll
    for (int o = 32; o > 0; o >>= 1) {
      t1 += __shfl_down(t1, o);
      t2 += __shfl_down(t2, o);
    }
    if (lane == 0) {
      atomicAdd(&acc[5], t1);
      atomicAdd(&acc[6], t2);
    }
  }
  static_for<45>([&](auto r) {
    double v = A[r];
#pragma unroll
    for (int o = 32; o > 0; o >>= 1) v += __shfl_down(v, o);
    if (lane == 0) atomicAdd(&acc[7 + r], v);
  });
}

// ============================================================
// Kernel 5: solve (own kernel -> registerizes; R7/R10 evidence).
// Applies D*M*D scaling then the rank-2 + denormalize pipeline.
// ============================================================
__global__ __launch_bounds__(64, 1) void ff_solve(const double* __restrict__ acc,
                                                  float* __restrict__ outF) {
  if (threadIdx.x != 0 || blockIdx.x != 0) return;
  const double WS = acc[0];
  const double M1X = acc[1] / WS, M1Y = acc[2] / WS;
  const double M2X = acc[3] / WS, M2Y = acc[4] / WS;
  const double S1 = sqrt(2.0) / (acc[5] / WS + 1e-8);
  const double S2 = sqrt(2.0) / (acc[6] / WS + 1e-8);
  double M[45];
  static_for<45>([&](auto r) { M[r] = acc[7 + r]; });
  // apply D * M * D, D_(3i+j) = S2^[i<2] * S1^[j<2]
  static_for<9>([&](auto R) {
    static_for<9>([&](auto C) {
      constexpr int r = decltype(R)::value;
      constexpr int c = decltype(C)::value;
      if constexpr (c <= r) {
        const double sr = ((r / 3) < 2 ? S2 : 1.0) * ((r % 3) < 2 ? S1 : 1.0);
        const double sc = ((c / 3) < 2 ? S2 : 1.0) * ((c % 3) < 2 ? S1 : 1.0);
        M[PIX(r, c)] *= sr * sc;
      }
    });
  });
  solveF(M, S1, M1X, M1Y, S2, M2X, M2Y, outF);
}

// ============================================================
// Host launcher — 5 dispatches (R10 structure, float2 staging)
// ============================================================
extern "C" void kernel_launch(void* const* d_in, const int* in_sizes, int n_in,
                              void* d_out, int out_size, void* d_ws, size_t ws_size,
                              hipStream_t stream) {
  const float* pts1 = (const float*)d_in[0];
  const float* pts2 = (const float*)d_in[1];
  const int* samples = (const int*)d_in[2];
  const int N = in_sizes[0] / 3;      // 16384
  const int iters = in_sizes[2] / 8;  // 4096

  // workspace layout (16B-aligned start)
  float2* P1 = (float2*)d_ws;                      // N float2
  float2* P2 = P1 + N;                             // N float2
  double* acc = (double*)(P2 + N);                 // 52 doubles
  float* models = (float*)(acc + 52);              // iters*9
  float* ml = models + (size_t)iters * 9;          // iters
  float* ssum = ml + iters;                        // iters
  int* uniq = (int*)(ssum + iters);                // iters

  float* outF = (float*)d_out;  // 9 floats (Mbest)
  float* outmask = outF + 9;    // N floats (0/1)

  const int TB = (N + 255) / 256;
  const int FB = (iters + 63) / 64;
  prep_and_fit<<<TB + FB, 256, 0, stream>>>(pts1, pts2, samples, P1, P2,
                                            models, uniq, acc, N, iters, TB);
  sampson_stats4<<<(iters + 3) / 4, 256, 0, stream>>>(P1, P2, models, ml, ssum,
                                                      N, iters);
  selmask_p1<<<(N + 255) / 256, 256, 0, stream>>>(P1, P2, models, ml, ssum,
                                                  uniq, outmask, acc, N, iters);
  ff_p23<<<(N + 1023) / 1024, 256, 0, stream>>>(outmask, P1, P2, acc, N);
  ff_solve<<<1, 64, 0, stream>>>(acc, outF);
}